// Round 3
// baseline (469.045 us; speedup 1.0000x reference)
//
#include <hip/hip_runtime.h>
#include <hip/hip_bf16.h>

// out[i] = probs[X[i,0]*125000 + X[i,1]*2500 + X[i,2]*50 + X[i,3]]
//
// Round-2 post-mortem: FETCH 482 MB is the STRUCTURAL floor for random
// gathers — per-XCD footprint (25 MB table) >> per-XCD L2 (4 MB) -> ~83%
// miss, and random 64B L2-miss traffic caps at ~3.7 TB/s.
// Round-3 design: XCD-sliced two-pass.
//   K1: idx[i] = ravel(X[i])            (pure 160 MB stream)
//   K2: each XCD scans all idx (nt loads -> don't evict L2) and handles only
//       idx in its own 3.125 MB table slice (L2-resident -> gathers hit L2).
//       Slice = actual HW_REG_XCC_ID; per-slice atomic work queues in d_ws
//       guarantee every sample is processed once per slice regardless of
//       block->XCD dispatch.

typedef int v4i __attribute__((ext_vector_type(4)));

#define TABLE_SIZE 6250000
#define N_SLICES   8
#define SLICE_SZ   ((TABLE_SIZE + N_SLICES - 1) / N_SLICES)  // 781250 floats = 3.125 MB
#define CHUNK      4096                                       // samples per steal

__device__ __forceinline__ int get_xcc_id() {
    int x;
    asm volatile("s_getreg_b32 %0, hwreg(HW_REG_XCC_ID)" : "=s"(x));
    return x & 7;
}

// ---- K1: flat index precompute (streaming) ----
__global__ __launch_bounds__(256) void k_index(const v4i* __restrict__ X,
                                               int* __restrict__ idx, int n) {
    int i = blockIdx.x * blockDim.x + threadIdx.x;
    if (i < n) {
        v4i x = __builtin_nontemporal_load(&X[i]);
        int id = x.x * 125000 + x.y * 2500 + x.z * 50 + x.w;
        __builtin_nontemporal_store(id, &idx[i]);
    }
}

// ---- K2: XCD-sliced gather with per-slice work stealing ----
__global__ __launch_bounds__(256) void k_gather(const int* __restrict__ idx,
                                                const float* __restrict__ probs,
                                                float* __restrict__ out,
                                                int* __restrict__ counters, int n) {
    const int xcc = get_xcc_id();
    const int lo = xcc * SLICE_SZ;
    const int hi = lo + SLICE_SZ;
    const v4i* idx4 = (const v4i*)idx;
    __shared__ int s_c;

    for (;;) {
        if (threadIdx.x == 0) s_c = atomicAdd(&counters[xcc], CHUNK);
        __syncthreads();
        int c = s_c;
        __syncthreads();
        if (c >= n) break;

        #pragma unroll
        for (int k = 0; k < CHUNK / (256 * 4); ++k) {
            int i0 = c + (threadIdx.x + k * 256) * 4;
            if (i0 + 3 < n) {
                v4i v = __builtin_nontemporal_load(&idx4[i0 >> 2]);
                if (v.x >= lo && v.x < hi) __builtin_nontemporal_store(probs[v.x], &out[i0]);
                if (v.y >= lo && v.y < hi) __builtin_nontemporal_store(probs[v.y], &out[i0 + 1]);
                if (v.z >= lo && v.z < hi) __builtin_nontemporal_store(probs[v.z], &out[i0 + 2]);
                if (v.w >= lo && v.w < hi) __builtin_nontemporal_store(probs[v.w], &out[i0 + 3]);
            } else {
                for (int m = 0; m < 4; ++m) {
                    int i = i0 + m;
                    if (i < n) {
                        int v = idx[i];
                        if (v >= lo && v < hi) __builtin_nontemporal_store(probs[v], &out[i]);
                    }
                }
            }
        }
    }
}

// ---- fallback (round-1 kernel) if workspace is too small ----
__global__ __launch_bounds__(256) void k_simple(const v4i* __restrict__ X,
                                                const float* __restrict__ probs,
                                                float* __restrict__ out, int n) {
    int i = blockIdx.x * blockDim.x + threadIdx.x;
    if (i < n) {
        v4i x = X[i];
        out[i] = probs[x.x * 125000 + x.y * 2500 + x.z * 50 + x.w];
    }
}

extern "C" void kernel_launch(void* const* d_in, const int* in_sizes, int n_in,
                              void* d_out, int out_size, void* d_ws, size_t ws_size,
                              hipStream_t stream) {
    const float* probs = (const float*)d_in[0];
    const v4i*   X     = (const v4i*)d_in[1];   // [N,4] int32 rows
    float* out = (float*)d_out;
    int n = out_size;  // 8,000,000

    size_t need = 256 + (size_t)n * sizeof(int);
    if (ws_size < need) {
        int block = 256;
        k_simple<<<(n + block - 1) / block, block, 0, stream>>>(X, probs, out, n);
        return;
    }

    int* counters = (int*)d_ws;                 // 8 ints (first 256 B)
    int* idx      = (int*)((char*)d_ws + 256);  // 32 MB, 16B-aligned

    hipMemsetAsync(counters, 0, 256, stream);   // ws is re-poisoned each launch

    int block = 256;
    k_index<<<(n + block - 1) / block, block, 0, stream>>>(X, idx, n);
    k_gather<<<2048, block, 0, stream>>>(idx, probs, out, counters, n);
}

// Round 4
// 306.578 us; speedup vs baseline: 1.5299x; 1.5299x over previous
//
#include <hip/hip_runtime.h>
#include <hip/hip_bf16.h>

// out[i] = probs[X[i,0]*125000 + X[i,1]*2500 + X[i,2]*50 + X[i,3]]
//
// Round-3 post-mortem: XCD-sliced two-pass fixed reads (FETCH 144 MB) but
// sparse per-XCD stores amplified writes 32->283 MB. Reverted.
// Round-1/2 re-analysis: VGPR=12 proves the compiler kept ~1 gather in
// flight; 26 waves/CU x 1 miss / ~400cyc = 0.065 fills/cyc/CU == measured
// 0.064. MLP-bound, not BW-bound. Fix: VPT=8 with a branch-free fast path
// so 8 independent gathers are genuinely outstanding per thread.

typedef int v4i __attribute__((ext_vector_type(4)));

constexpr int VPT   = 8;
constexpr int BLOCK = 256;
constexpr int TILE  = BLOCK * VPT;  // 2048 samples/block

__global__ __launch_bounds__(256) void jc_mlp_kernel(
    const v4i* __restrict__ X,
    const float* __restrict__ probs,
    float* __restrict__ out,
    int n)
{
    int base = blockIdx.x * TILE + threadIdx.x;

    if ((blockIdx.x + 1) * TILE <= n) {
        // ---- branch-free fast path: 8 gathers in flight ----
        v4i x[VPT];
        #pragma unroll
        for (int v = 0; v < VPT; ++v)
            x[v] = __builtin_nontemporal_load(&X[base + v * BLOCK]);

        int idx[VPT];
        #pragma unroll
        for (int v = 0; v < VPT; ++v)
            idx[v] = x[v].x * 125000 + x[v].y * 2500 + x[v].z * 50 + x[v].w;

        float val[VPT];
        #pragma unroll
        for (int v = 0; v < VPT; ++v)
            val[v] = probs[idx[v]];        // cached: table has L2/L3 reuse

        #pragma unroll
        for (int v = 0; v < VPT; ++v)
            __builtin_nontemporal_store(val[v], &out[base + v * BLOCK]);
    } else {
        // ---- tail block (8M % 2048 = 512 samples) ----
        for (int v = 0; v < VPT; ++v) {
            int i = base + v * BLOCK;
            if (i < n) {
                v4i xv = X[i];
                out[i] = probs[xv.x * 125000 + xv.y * 2500 + xv.z * 50 + xv.w];
            }
        }
    }
}

extern "C" void kernel_launch(void* const* d_in, const int* in_sizes, int n_in,
                              void* d_out, int out_size, void* d_ws, size_t ws_size,
                              hipStream_t stream) {
    const float* probs = (const float*)d_in[0];
    const v4i*   X     = (const v4i*)d_in[1];   // [N,4] int32 rows
    float* out = (float*)d_out;

    int n = out_size;  // 8,000,000
    int grid = (n + TILE - 1) / TILE;  // 3907
    jc_mlp_kernel<<<grid, BLOCK, 0, stream>>>(X, probs, out, n);
}